// Round 8
// baseline (740.133 us; speedup 1.0000x reference)
//
#include <hip/hip_runtime.h>
#include <math.h>

// VQ-VAE quantizer. Outputs in d_out (float32, flat, concat):
//   [0] loss | [1..16777216] quantized_st NCHW | [16777217] perplexity
//   [16777218 ..) encodings one-hot [262144,512]
//
// R19: split one-hot zero-fill into vq_prep with PLAIN stores.
// The R11-R18 matrix: any one-hot strategy INSIDE vq_main runs ~2.9 TB/s
// (NT zero+fixup 726 / plain zero+fixup 774 / plain one-pass 738; R17
// counters: 672 MB in ~230 us). rocclr's standalone plain fill on this
// same buffer runs 6.2 TB/s every round. R12's split test used an NT
// fill (~2 TB/s standalone -> +55 total) so the fast cell of the matrix
// -- standalone + plain -- was never tested. This is that test:
//   vq_prep blocks 9..4104: contiguous f32x4 plain-store sweeps, no
//   barriers/drains (bit-identical pattern to the 6.2 TB/s rocclr fill).
//   vq_main = R14 minus the zero stream: NT quantized stores, LDS-fp32
//   epilogue, 4-byte NT one-hot fixups + 16-way replica hist atomics at
//   the very end (fire-and-forget; stream order after prep guarantees
//   zeros land first -- R12-validated).
//
// ws (floats): [0..8191] hist replicas (ints, 16x512), [8192..8703] b_k,
//              [8704..12799] loss partials, [12800..29183] e-bf16 (64 KB).

#define NTOK    262144
#define KCODES  512
#define DDIM    64
#define CSTRIDE 16384
#define IMG     1048576
#define QOFF    1
#define POFF    16777217
#define EOFF    16777218
#define BK      8192
#define LOSS    8704
#define EBF     12800
#define SUBFLT  32768      // floats per one-hot sub-region (64 rows x 512)

typedef short bf16x8 __attribute__((ext_vector_type(8)));
typedef float f32x4  __attribute__((ext_vector_type(4)));

__device__ __forceinline__ unsigned short f2bf(float f) {
    unsigned u = __float_as_uint(f);
    return (unsigned short)((u + 0x7fffu + ((u >> 16) & 1u)) >> 16);  // RTN
}

__device__ __forceinline__ float np_pairwise_sq64(const float* v) {
    float r[8];
#pragma unroll
    for (int j = 0; j < 8; ++j) r[j] = __fmul_rn(v[j], v[j]);
#pragma unroll
    for (int i = 8; i < 64; i += 8) {
#pragma unroll
        for (int j = 0; j < 8; ++j)
            r[j] = __fadd_rn(r[j], __fmul_rn(v[i + j], v[i + j]));
    }
    float s01 = __fadd_rn(r[0], r[1]);
    float s23 = __fadd_rn(r[2], r[3]);
    float s45 = __fadd_rn(r[4], r[5]);
    float s67 = __fadd_rn(r[6], r[7]);
    return __fadd_rn(__fadd_rn(s01, s23), __fadd_rn(s45, s67));
}

// blocks 0..7: emb -> bf16 scratch; block 8: b_k = ||e_k||^2;
// blocks 9..4104: one-hot zero-fill, PLAIN stores, contiguous sweeps
// (structurally identical to the 6.2 TB/s rocclr fillBuffer).
__global__ __launch_bounds__(256) void vq_prep(const float* __restrict__ emb,
                                               float* __restrict__ out,
                                               float* __restrict__ ws) {
    const int tid = threadIdx.x, blk = blockIdx.x;
    if (blk >= 9) {
        f32x4* sub4 = (f32x4*)(out + EOFF) + (size_t)(blk - 9) * 8192;
        const f32x4 z4 = {0.f, 0.f, 0.f, 0.f};
#pragma unroll
        for (int ii = 0; ii < 32; ++ii)
            sub4[ii * 256 + tid] = z4;           // plain: L2 writeback path
        return;
    }
    if (blk < 8) {
        unsigned short* ebf = (unsigned short*)(ws + EBF);
#pragma unroll
        for (int ii = 0; ii < 16; ++ii) {
            int t = blk * 4096 + ii * 256 + tid;     // linear [code][d]
            ebf[t] = f2bf(emb[t]);
        }
    } else {
#pragma unroll
        for (int r = 0; r < 2; ++r) {
            const int k = tid * 2 + r;
            const float* e = emb + (size_t)k * DDIM;
            float v[64];
#pragma unroll
            for (int i = 0; i < 64; ++i) v[i] = e[i];
            ws[BK + k] = np_pairwise_sq64(v);
        }
    }
}

// ---- fused main: MFMA distances + argmin + quantized/loss/fixups --------
__global__ __launch_bounds__(256, 4) void vq_main(const float* __restrict__ in,
                                                  const float* __restrict__ emb,
                                                  float* __restrict__ out,
                                                  float* __restrict__ ws) {
    __shared__ unsigned short xbf[64 * 68];      // [tok][d] bf16 +pad, 8.5 KB
    __shared__ float          xls[64 * 64];      // [ch][tok] fp32, 16 KB
    __shared__ float          bsh[512];
    __shared__ int            idx_sh[64];
    __shared__ float          red[4];

    const int tid = threadIdx.x, blk = blockIdx.x;
    const int T0 = blk * 64, b = T0 >> 14, hw0 = T0 & 16383;

    // input loads (the only VMEM gating the first barrier)
    const float4* gx = (const float4*)(in + (size_t)b * IMG + hw0);
    float4 g[4];
#pragma unroll
    for (int jj = 0; jj < 4; ++jj) {
        int t = tid + jj * 256;                  // t = c*16 + q
        g[jj] = gx[(size_t)(t >> 4) * (CSTRIDE / 4) + (t & 15)];
    }
    const float bk0 = ws[BK + tid];
    const float bk1 = ws[BK + 256 + tid];

    // stage x: bf16 transposed [tok][d] for MFMA + fp32 [ch][tok] for epilogue
#pragma unroll
    for (int jj = 0; jj < 4; ++jj) {
        int t = tid + jj * 256;
        int c = t >> 4, q4 = (t & 15) * 4;       // channel, token group
        *(float4*)(&xls[c * 64 + q4]) = g[jj];
        xbf[(q4 + 0) * 68 + c] = f2bf(g[jj].x);
        xbf[(q4 + 1) * 68 + c] = f2bf(g[jj].y);
        xbf[(q4 + 2) * 68 + c] = f2bf(g[jj].z);
        xbf[(q4 + 3) * 68 + c] = f2bf(g[jj].w);
    }
    bsh[tid]       = bk0;
    bsh[256 + tid] = bk1;
    __syncthreads();

    const int l = tid & 63, w = tid >> 6;            // lane, wave
    const int lm = l & 15, lg = l >> 4;

    // A-fragments: x[tok = w*16+lm][d = kt*32 + lg*8 + j]
    const bf16x8 a0 = *(const bf16x8*)(xbf + (w * 16 + lm) * 68 + lg * 8);
    const bf16x8 a1 = *(const bf16x8*)(xbf + (w * 16 + lm) * 68 + 32 + lg * 8);

    const unsigned short* ebf = (const unsigned short*)(ws + EBF);
    const unsigned short* ep  = ebf + lm * 64 + lg * 8;

    float dmin[4]; int idx[4];
#pragma unroll
    for (int r = 0; r < 4; ++r) { dmin[r] = 3.402823466e38f; idx[r] = 0; }
    const f32x4 zero = {0.f, 0.f, 0.f, 0.f};

#pragma unroll 4
    for (int nt = 0; nt < 32; ++nt) {                // codes ascending
        bf16x8 b0 = *(const bf16x8*)(ep + nt * 1024);
        bf16x8 b1 = *(const bf16x8*)(ep + nt * 1024 + 32);
        f32x4 acc = __builtin_amdgcn_mfma_f32_16x16x32_bf16(a0, b0, zero, 0, 0, 0);
        acc       = __builtin_amdgcn_mfma_f32_16x16x32_bf16(a1, b1, acc,  0, 0, 0);
        const int   code = nt * 16 + lm;
        const float bk   = bsh[code];
#pragma unroll
        for (int r = 0; r < 4; ++r) {                // token = w*16 + lg*4 + r
            float s = fmaf(-2.0f, acc[r], bk);
            if (s < dmin[r]) { dmin[r] = s; idx[r] = code; }
        }
    }

    // merge across the 16 code-lanes (xor over bits 0..3 of lane)
#pragma unroll
    for (int m = 1; m < 16; m <<= 1) {
#pragma unroll
        for (int r = 0; r < 4; ++r) {
            float od = __shfl_xor(dmin[r], m, 64);
            int   oi = __shfl_xor(idx[r],  m, 64);
            if (od < dmin[r] || (od == dmin[r] && oi < idx[r])) {
                dmin[r] = od; idx[r] = oi;
            }
        }
    }
    if (lm == 0) {
#pragma unroll
        for (int r = 0; r < 4; ++r) idx_sh[w * 16 + lg * 4 + r] = idx[r];
    }
    __syncthreads();   // idx_sh ready

    // epilogue: quantized_st + loss (x from LDS fp32, e via float4 gather)
    const int tl = tid & 63, chh = (tid >> 6) * 16;  // 4 lanes per token
    const int id = idx_sh[tl];

    const float4* e4 = (const float4*)(emb + (size_t)id * DDIM + chh);
    float4 ev[4];
#pragma unroll
    for (int k = 0; k < 4; ++k) ev[k] = e4[k];

    float* q = out + QOFF + (size_t)b * IMG + hw0 + tl;
    float lsum = 0.f;
#pragma unroll
    for (int cc = 0; cc < 16; ++cc) {
        float x   = xls[(chh + cc) * 64 + tl];
        float ee  = ((const float*)&ev[cc >> 2])[cc & 3];     // static after unroll
        float dqx = __fsub_rn(ee, x);
        lsum = __fadd_rn(lsum, __fmul_rn(dqx, dqx));
        __builtin_nontemporal_store(__fadd_rn(x, dqx),
                                    q + (size_t)(chh + cc) * CSTRIDE);
    }
#pragma unroll
    for (int off = 32; off > 0; off >>= 1) lsum += __shfl_down(lsum, off, 64);
    if ((tid & 63) == 0) red[tid >> 6] = lsum;
    __syncthreads();
    if (tid == 0) ws[LOSS + blk] = red[0] + red[1] + red[2] + red[3];

    // one-hot 1.0 fixups (zeros laid down by vq_prep; stream order
    // guarantees they precede us -- R12-validated) + hist atomics.
    // Fire-and-forget: no barrier follows either.
    if (tid < 64) {
        const int ix = idx_sh[tid];
        __builtin_nontemporal_store(
            1.0f, out + EOFF + (size_t)blk * SUBFLT + tid * 512 + ix);
        atomicAdd((int*)ws + ((blk & 15) << 9) + ix, 1);
    }
}

__global__ void vq_final(float* __restrict__ out, const float* __restrict__ ws) {
    __shared__ float sl[512], sp[512];
    int t = threadIdx.x;                              // 512 threads, 1 block
    float s = 0.f;
#pragma unroll
    for (int r = 0; r < 8; ++r) s += ws[LOSS + t + 512 * r];
    sl[t] = s;
    int cnt = 0;
#pragma unroll
    for (int r = 0; r < 16; ++r) cnt += ((const int*)ws)[(r << 9) + t];
    float p = (float)cnt * (1.0f / 262144.0f);
    sp[t] = p * logf(p + 1e-10f);
    __syncthreads();
    for (int off = 256; off > 0; off >>= 1) {
        if (t < off) { sl[t] += sl[t + off]; sp[t] += sp[t + off]; }
        __syncthreads();
    }
    if (t == 0) {
        float m = sl[0] * (1.0f / 16777216.0f);       // /2^24 exact
        out[0]    = __fadd_rn(m, __fmul_rn(0.25f, m));
        out[POFF] = expf(-sp[0]);
    }
}

extern "C" void kernel_launch(void* const* d_in, const int* in_sizes, int n_in,
                              void* d_out, int out_size, void* d_ws, size_t ws_size,
                              hipStream_t stream) {
    const float* in  = (const float*)d_in[0];
    const float* emb = (const float*)d_in[1];
    float* out = (float*)d_out;
    float* ws  = (float*)d_ws;   // needs ~117 KB; harness scratch is larger

    (void)hipMemsetAsync(d_ws, 0, 16 * 512 * sizeof(int), stream); // hist replicas
    hipLaunchKernelGGL(vq_prep,  dim3(4105), dim3(256), 0, stream, emb, out, ws);
    hipLaunchKernelGGL(vq_main,  dim3(4096), dim3(256), 0, stream, in, emb, out, ws);
    hipLaunchKernelGGL(vq_final, dim3(1),    dim3(512), 0, stream, out, ws);
}